// Round 1
// baseline (6493.549 us; speedup 1.0000x reference)
//
#include <hip/hip_runtime.h>
#include <math.h>

#define Bb 4
#define Tt 2048
#define Hh 16
#define Dd 128
#define ATTN 2048
#define Mm 8192   // Bb*Tt

typedef unsigned short u16;

__device__ __forceinline__ float bf2f(u16 h) {
    union { unsigned int u; float f; } x;
    x.u = ((unsigned int)h) << 16;
    return x.f;
}
__device__ __forceinline__ u16 f2bf(float f) {
    union { float f; unsigned int u; } x;
    x.f = f;
    unsigned int r = x.u + 0x7fffu + ((x.u >> 16) & 1u);  // RNE
    return (u16)(r >> 16);
}
__device__ __forceinline__ void unpack4(const u16* p, float* f) {
    uint2 u = *(const uint2*)p;
    union { unsigned int u; float f; } a, b, c, d;
    a.u = (u.x << 16); b.u = (u.x & 0xffff0000u);
    c.u = (u.y << 16); d.u = (u.y & 0xffff0000u);
    f[0] = a.f; f[1] = b.f; f[2] = c.f; f[3] = d.f;
}

// ---- RoPE cos/sin table: reference recomputes from FREQ_BASE=10000 (the
// freqs_cos/freqs_sin inputs are UNUSED by the reference). fp64 for accuracy.
__global__ __launch_bounds__(256) void freq_kernel(float* __restrict__ cost,
                                                   float* __restrict__ sint) {
    int idx = blockIdx.x * 256 + threadIdx.x;   // Tt*64 = 131072
    if (idx >= Tt * 64) return;
    int t = idx >> 6, i = idx & 63;
    double inv = exp(-((double)(2 * i) / 128.0) * log(10000.0));
    double ang = (double)t * inv;
    cost[idx] = (float)cos(ang);
    sint[idx] = (float)sin(ang);
}

// ---- fp32 GEMM: C[m,n] = sum_k A[m,k]*W[n,k] + bias[n]
// MODE 0: fp32 plain (M x N) row-major.  MODE 1: bf16 to (B,H,T,D) layout.
// Tile 128x128, K-tile 16, 256 threads, 8x8 per thread, padded LDS (132).
template<int MODE>
__global__ __launch_bounds__(256) void gemm_bt(const float* __restrict__ A,
                                               const float* __restrict__ W,
                                               const float* __restrict__ bias,
                                               void* __restrict__ Cout) {
    const int K = 2048, N = 2048;
    __shared__ float As[16][132];
    __shared__ float Ws[16][132];
    const int tid = threadIdx.x;
    const int tx = tid & 15, ty = tid >> 4;
    const int m0 = blockIdx.y * 128, n0 = blockIdx.x * 128;
    const int lr = tid >> 2;            // 0..63
    const int lk = (tid & 3) << 2;      // 0,4,8,12
    const float* Ap = A + (size_t)(m0 + lr) * K + lk;
    const float* Wp = W + (size_t)(n0 + lr) * K + lk;
    float acc[8][8];
#pragma unroll
    for (int i = 0; i < 8; i++)
#pragma unroll
        for (int j = 0; j < 8; j++) acc[i][j] = 0.f;

    for (int k0 = 0; k0 < K; k0 += 16) {
        float4 a0 = *(const float4*)(Ap);
        float4 a1 = *(const float4*)(Ap + (size_t)64 * K);
        float4 w0 = *(const float4*)(Wp);
        float4 w1 = *(const float4*)(Wp + (size_t)64 * K);
        __syncthreads();
        As[lk + 0][lr] = a0.x; As[lk + 1][lr] = a0.y;
        As[lk + 2][lr] = a0.z; As[lk + 3][lr] = a0.w;
        As[lk + 0][lr + 64] = a1.x; As[lk + 1][lr + 64] = a1.y;
        As[lk + 2][lr + 64] = a1.z; As[lk + 3][lr + 64] = a1.w;
        Ws[lk + 0][lr] = w0.x; Ws[lk + 1][lr] = w0.y;
        Ws[lk + 2][lr] = w0.z; Ws[lk + 3][lr] = w0.w;
        Ws[lk + 0][lr + 64] = w1.x; Ws[lk + 1][lr + 64] = w1.y;
        Ws[lk + 2][lr + 64] = w1.z; Ws[lk + 3][lr + 64] = w1.w;
        __syncthreads();
#pragma unroll
        for (int kk = 0; kk < 16; kk++) {
            float a[8], w[8];
            *(float4*)(a)     = *(const float4*)&As[kk][ty * 4];
            *(float4*)(a + 4) = *(const float4*)&As[kk][64 + ty * 4];
            *(float4*)(w)     = *(const float4*)&Ws[kk][tx * 4];
            *(float4*)(w + 4) = *(const float4*)&Ws[kk][64 + tx * 4];
#pragma unroll
            for (int i = 0; i < 8; i++)
#pragma unroll
                for (int j = 0; j < 8; j++)
                    acc[i][j] = fmaf(a[i], w[j], acc[i][j]);
        }
        Ap += 16; Wp += 16;
    }

    if (MODE == 0) {
        float* C = (float*)Cout;
#pragma unroll
        for (int ih = 0; ih < 2; ih++)
#pragma unroll
            for (int i = 0; i < 4; i++) {
                int m = m0 + ih * 64 + ty * 4 + i;
#pragma unroll
                for (int jh = 0; jh < 2; jh++) {
                    int nl = jh * 64 + tx * 4;
                    float4 v;
                    v.x = acc[ih * 4 + i][jh * 4 + 0] + bias[n0 + nl + 0];
                    v.y = acc[ih * 4 + i][jh * 4 + 1] + bias[n0 + nl + 1];
                    v.z = acc[ih * 4 + i][jh * 4 + 2] + bias[n0 + nl + 2];
                    v.w = acc[ih * 4 + i][jh * 4 + 3] + bias[n0 + nl + 3];
                    *(float4*)&C[(size_t)m * N + n0 + nl] = v;
                }
            }
    } else {
        // bf16 out to (B, H, T, D); 128-wide N-tile == exactly one head
        u16* C = (u16*)Cout;
        const int h = n0 >> 7;
#pragma unroll
        for (int ih = 0; ih < 2; ih++)
#pragma unroll
            for (int i = 0; i < 4; i++) {
                int m = m0 + ih * 64 + ty * 4 + i;
                int b = m >> 11, t = m & 2047;
                size_t base = (((size_t)(b * Hh + h)) * Tt + t) * Dd;
#pragma unroll
                for (int jh = 0; jh < 2; jh++) {
                    int nl = jh * 64 + tx * 4;
                    union { ushort4 u; u16 s[4]; } pk;
                    pk.s[0] = f2bf(acc[ih * 4 + i][jh * 4 + 0] + bias[n0 + nl + 0]);
                    pk.s[1] = f2bf(acc[ih * 4 + i][jh * 4 + 1] + bias[n0 + nl + 1]);
                    pk.s[2] = f2bf(acc[ih * 4 + i][jh * 4 + 2] + bias[n0 + nl + 2]);
                    pk.s[3] = f2bf(acc[ih * 4 + i][jh * 4 + 3] + bias[n0 + nl + 3]);
                    *(ushort4*)&C[base + nl] = pk.u;
                }
            }
    }
}

// ---- RoPE applied in-place to q,k (bf16, (B,H,T,D)); pairs along D.
__global__ __launch_bounds__(256) void rope_kernel(u16* __restrict__ q,
                                                   u16* __restrict__ k,
                                                   const float* __restrict__ cost,
                                                   const float* __restrict__ sint) {
    int p = blockIdx.x * 256 + threadIdx.x;    // Bb*Hh*Tt*64 = 8388608 pairs
    int i = p & 63;
    int t = (p >> 6) & 2047;
    float c = cost[t * 64 + i], s = sint[t * 64 + i];
    size_t off = (size_t)p * 2;
    ushort2 qv = *(ushort2*)(q + off);
    float q0 = bf2f(qv.x), q1 = bf2f(qv.y);
    qv.x = f2bf(q0 * c - q1 * s);
    qv.y = f2bf(q0 * s + q1 * c);
    *(ushort2*)(q + off) = qv;
    ushort2 kv = *(ushort2*)(k + off);
    float k0 = bf2f(kv.x), k1 = bf2f(kv.y);
    kv.x = f2bf(k0 * c - k1 * s);
    kv.y = f2bf(k0 * s + k1 * c);
    *(ushort2*)(k + off) = kv;
}

// ---- Flash attention (causal). Br=Bc=64, one (b,h,q-tile) per block.
// Thread (tx,ty) owns S rows ty*4..+3, cols tx*4..+3; row reduce = 16-lane shfl.
__global__ __launch_bounds__(256) void flash_kernel(const u16* __restrict__ Q,
                                                    const u16* __restrict__ Kg,
                                                    const u16* __restrict__ V,
                                                    float* __restrict__ O) {
    __shared__ u16 Qs[64][132];
    __shared__ u16 Ks[64][132];
    __shared__ u16 Vs[64][132];
    __shared__ u16 Ps[64][68];
    const int tid = threadIdx.x;
    const int tx = tid & 15, ty = tid >> 4;
    const int qb = blockIdx.x, bh = blockIdx.y;
    const int q0 = qb * 64;
    const size_t qoff = ((size_t)bh * Tt + q0) * Dd;
#pragma unroll
    for (int ii = 0; ii < 8; ii++) {
        int e = tid + ii * 256;                 // 0..2047
        int row = e >> 5, c4 = (e & 31) * 4;
        *(ushort4*)&Qs[row][c4] = *(const ushort4*)&Q[qoff + (size_t)row * Dd + c4];
    }
    float m_i[4], l_i[4], Oacc[4][8];
#pragma unroll
    for (int i = 0; i < 4; i++) {
        m_i[i] = -INFINITY; l_i[i] = 0.f;
#pragma unroll
        for (int d = 0; d < 8; d++) Oacc[i][d] = 0.f;
    }
    const float scale = 0.08838834764831843f;   // 1/sqrt(128)
    const int nk = qb + 1;
    for (int kt = 0; kt < nk; kt++) {
        const size_t koff = ((size_t)bh * Tt + kt * 64) * Dd;
        __syncthreads();    // previous iter's PV reads done before overwrite
#pragma unroll
        for (int ii = 0; ii < 8; ii++) {
            int e = tid + ii * 256;
            int row = e >> 5, c4 = (e & 31) * 4;
            *(ushort4*)&Ks[row][c4] = *(const ushort4*)&Kg[koff + (size_t)row * Dd + c4];
            *(ushort4*)&Vs[row][c4] = *(const ushort4*)&V[koff + (size_t)row * Dd + c4];
        }
        __syncthreads();
        // S = Q K^T over D=128
        float S[4][4];
#pragma unroll
        for (int i = 0; i < 4; i++)
#pragma unroll
            for (int j = 0; j < 4; j++) S[i][j] = 0.f;
#pragma unroll 4
        for (int c4 = 0; c4 < 32; c4++) {
            float qv[4][4], kv[4][4];
#pragma unroll
            for (int i = 0; i < 4; i++) unpack4(&Qs[ty * 4 + i][c4 * 4], qv[i]);
#pragma unroll
            for (int j = 0; j < 4; j++) unpack4(&Ks[tx * 4 + j][c4 * 4], kv[j]);
#pragma unroll
            for (int i = 0; i < 4; i++)
#pragma unroll
                for (int j = 0; j < 4; j++)
#pragma unroll
                    for (int kk = 0; kk < 4; kk++)
                        S[i][j] = fmaf(qv[i][kk], kv[j][kk], S[i][j]);
        }
#pragma unroll
        for (int i = 0; i < 4; i++)
#pragma unroll
            for (int j = 0; j < 4; j++) S[i][j] *= scale;
        if (kt == qb) {     // diagonal tile: mask k > q
#pragma unroll
            for (int i = 0; i < 4; i++)
#pragma unroll
                for (int j = 0; j < 4; j++)
                    if (tx * 4 + j > ty * 4 + i) S[i][j] = -INFINITY;
        }
        // online softmax (row state lives in the 16 lanes sharing ty)
#pragma unroll
        for (int i = 0; i < 4; i++) {
            float mx = fmaxf(fmaxf(S[i][0], S[i][1]), fmaxf(S[i][2], S[i][3]));
#pragma unroll
            for (int off = 8; off >= 1; off >>= 1)
                mx = fmaxf(mx, __shfl_xor(mx, off, 64));
            float mnew = fmaxf(m_i[i], mx);
            float alpha = __expf(m_i[i] - mnew);
            float p0 = __expf(S[i][0] - mnew);
            float p1 = __expf(S[i][1] - mnew);
            float p2 = __expf(S[i][2] - mnew);
            float p3 = __expf(S[i][3] - mnew);
            float rs = (p0 + p1) + (p2 + p3);
#pragma unroll
            for (int off = 8; off >= 1; off >>= 1)
                rs += __shfl_xor(rs, off, 64);
            l_i[i] = l_i[i] * alpha + rs;
            m_i[i] = mnew;
#pragma unroll
            for (int d = 0; d < 8; d++) Oacc[i][d] *= alpha;
            union { ushort4 u; u16 s[4]; } pk;
            pk.s[0] = f2bf(p0); pk.s[1] = f2bf(p1);
            pk.s[2] = f2bf(p2); pk.s[3] = f2bf(p3);
            *(ushort4*)&Ps[ty * 4 + i][tx * 4] = pk.u;
        }
        __syncthreads();
        // O += P V
#pragma unroll 4
        for (int c4 = 0; c4 < 16; c4++) {
            float pv[4][4];
#pragma unroll
            for (int i = 0; i < 4; i++) unpack4(&Ps[ty * 4 + i][c4 * 4], pv[i]);
#pragma unroll
            for (int cc = 0; cc < 4; cc++) {
                float vv[8];
                unpack4(&Vs[c4 * 4 + cc][tx * 4], vv);
                unpack4(&Vs[c4 * 4 + cc][64 + tx * 4], vv + 4);
#pragma unroll
                for (int i = 0; i < 4; i++)
#pragma unroll
                    for (int d = 0; d < 8; d++)
                        Oacc[i][d] = fmaf(pv[i][cc], vv[d], Oacc[i][d]);
            }
        }
    }
    // epilogue: normalize and store to (B, T, H*D) fp32
    const int b = bh >> 4, h = bh & 15;
#pragma unroll
    for (int i = 0; i < 4; i++) {
        float inv = 1.f / l_i[i];
        size_t rowoff = ((size_t)b * Tt + q0 + ty * 4 + i) * ATTN + (size_t)h * Dd;
        float4 v0, v1;
        v0.x = Oacc[i][0] * inv; v0.y = Oacc[i][1] * inv;
        v0.z = Oacc[i][2] * inv; v0.w = Oacc[i][3] * inv;
        v1.x = Oacc[i][4] * inv; v1.y = Oacc[i][5] * inv;
        v1.z = Oacc[i][6] * inv; v1.w = Oacc[i][7] * inv;
        *(float4*)&O[rowoff + tx * 4] = v0;
        *(float4*)&O[rowoff + 64 + tx * 4] = v1;
    }
}

extern "C" void kernel_launch(void* const* d_in, const int* in_sizes, int n_in,
                              void* d_out, int out_size, void* d_ws, size_t ws_size,
                              hipStream_t stream) {
    const float* x    = (const float*)d_in[0];
    // d_in[1], d_in[2] (freqs_cos/sin) are unused by the reference — recomputed.
    const float* wq_w = (const float*)d_in[3];
    const float* wq_b = (const float*)d_in[4];
    const float* wk_w = (const float*)d_in[5];
    const float* wk_b = (const float*)d_in[6];
    const float* wv_w = (const float*)d_in[7];
    const float* wv_b = (const float*)d_in[8];
    const float* wo_w = (const float*)d_in[9];
    const float* wo_b = (const float*)d_in[10];

    char* ws = (char*)d_ws;
    u16*   qb = (u16*)(ws);                       // 32 MB  bf16 (B,H,T,D)
    u16*   kb = (u16*)(ws + 33554432);            // 32 MB
    u16*   vb = (u16*)(ws + 67108864);            // 32 MB
    float* ob = (float*)(ws + 100663296);         // 64 MB  fp32 (B,T,ATTN)
    float* ct = (float*)(ws + 167772160);         // 0.5 MB
    float* st = (float*)(ws + 168296448);         // 0.5 MB

    freq_kernel<<<512, 256, 0, stream>>>(ct, st);
    dim3 gg(16, 64);
    gemm_bt<1><<<gg, 256, 0, stream>>>(x, wq_w, wq_b, qb);
    gemm_bt<1><<<gg, 256, 0, stream>>>(x, wk_w, wk_b, kb);
    gemm_bt<1><<<gg, 256, 0, stream>>>(x, wv_w, wv_b, vb);
    rope_kernel<<<32768, 256, 0, stream>>>(qb, kb, ct, st);
    flash_kernel<<<dim3(32, 64), 256, 0, stream>>>(qb, kb, vb, ob);
    gemm_bt<0><<<gg, 256, 0, stream>>>(ob, wo_w, wo_b, (float*)d_out);
}

// Round 2
// 927.559 us; speedup vs baseline: 7.0007x; 7.0007x over previous
//
#include <hip/hip_runtime.h>
#include <math.h>

#define Tt 2048
#define Hh 16
#define Dd 128
#define ATTN 2048

typedef unsigned short u16;
typedef __attribute__((ext_vector_type(8))) short short8;
typedef __attribute__((ext_vector_type(4))) float f32x4;

__device__ __forceinline__ float bf2f(u16 h) {
    union { unsigned int u; float f; } x;
    x.u = ((unsigned int)h) << 16;
    return x.f;
}
__device__ __forceinline__ u16 f2bf(float f) {
    union { float f; unsigned int u; } x;
    x.f = f;
    unsigned int r = x.u + 0x7fffu + ((x.u >> 16) & 1u);  // RNE
    return (u16)(r >> 16);
}
// async global->LDS, 16B per lane; lptr is wave-uniform base, HW adds lane*16.
__device__ __forceinline__ void gl_lds16(const void* g, void* l) {
    __builtin_amdgcn_global_load_lds(
        (const __attribute__((address_space(1))) unsigned int*)g,
        (__attribute__((address_space(3))) unsigned int*)l, 16, 0, 0);
}

// ---- RoPE cos/sin table (reference ignores freqs_cos/sin inputs; recompute).
__global__ __launch_bounds__(256) void freq_kernel(float* __restrict__ cost,
                                                   float* __restrict__ sint) {
    int idx = blockIdx.x * 256 + threadIdx.x;   // Tt*64
    if (idx >= Tt * 64) return;
    int t = idx >> 6, i = idx & 63;
    double inv = exp(-((double)(2 * i) / 128.0) * log(10000.0));
    double ang = (double)t * inv;
    cost[idx] = (float)cos(ang);
    sint[idx] = (float)sin(ang);
}

// ---- fp32 -> bf16 bulk convert (vectorized), n4 = elems/4
__global__ __launch_bounds__(256) void cvt_kernel(const float* __restrict__ in,
                                                  u16* __restrict__ out, int n4) {
    int i = blockIdx.x * 256 + threadIdx.x;
    if (i >= n4) return;
    float4 v = *(const float4*)(in + (size_t)i * 4);
    union { ushort4 u; u16 s[4]; } pk;
    pk.s[0] = f2bf(v.x); pk.s[1] = f2bf(v.y);
    pk.s[2] = f2bf(v.z); pk.s[3] = f2bf(v.w);
    *(ushort4*)(out + (size_t)i * 4) = pk.u;
}

// ---- bf16 MFMA GEMM: C[m,n] = sum_k A[m,k]*W[n,k] + bias[n]
// A: M x 2048 bf16 row-major, W: 2048 x 2048 bf16 row-major (B^T form).
// 128x128 tile, BK=32, 256 thr (4 waves, 2x2 wave grid, 64x64 each).
// MODE 0: fp32 (M,2048). MODE 1: bf16 (B,H,T,D). MODE 2: bf16 (B,H,D,T).
template<int MODE>
__global__ __launch_bounds__(256) void gemm_mfma(const u16* __restrict__ A,
                                                 const u16* __restrict__ W,
                                                 const float* __restrict__ bias,
                                                 void* __restrict__ Cout) {
    __shared__ u16 As[128 * 32];
    __shared__ u16 Ws[128 * 32];
    const int tid  = threadIdx.x;
    const int lane = tid & 63, w = tid >> 6;
    const int l15  = lane & 15, quad = lane >> 4;
    const int wm = w & 1, wn = w >> 1;
    const int m0 = blockIdx.y * 128, n0 = blockIdx.x * 128;

    const f32x4 zero4 = {0.f, 0.f, 0.f, 0.f};
    f32x4 acc[4][4];
#pragma unroll
    for (int mt = 0; mt < 4; mt++)
#pragma unroll
        for (int nt = 0; nt < 4; nt++) acc[mt][nt] = zero4;

    // staging: chunk c covers rows c*16..c*16+15, lane -> row c*16+(lane>>2),
    // k-granule (lane&3)*8. wave w owns chunks {2w, 2w+1} of A and of W.
    const int srow = w * 32 + (lane >> 2);
    const int scol = (lane & 3) * 8;
    const u16* Ag = A + (size_t)(m0 + srow) * 2048 + scol;
    const u16* Wg = W + (size_t)(n0 + srow) * 2048 + scol;
    u16* AsW = As + w * 1024;
    u16* WsW = Ws + w * 1024;

    for (int k0 = 0; k0 < 2048; k0 += 32) {
        __syncthreads();
        gl_lds16(Ag, AsW);
        gl_lds16(Ag + (size_t)16 * 2048, AsW + 512);
        gl_lds16(Wg, WsW);
        gl_lds16(Wg + (size_t)16 * 2048, WsW + 512);
        Ag += 32; Wg += 32;
        __syncthreads();
        const u16* ar = As + (wm * 64 + l15) * 32 + quad * 8;
        const u16* br = Ws + (wn * 64 + l15) * 32 + quad * 8;
        short8 af[4], bfr[4];
#pragma unroll
        for (int mt = 0; mt < 4; mt++) af[mt] = *(const short8*)(ar + mt * 512);
#pragma unroll
        for (int nt = 0; nt < 4; nt++) bfr[nt] = *(const short8*)(br + nt * 512);
#pragma unroll
        for (int mt = 0; mt < 4; mt++)
#pragma unroll
            for (int nt = 0; nt < 4; nt++)
                acc[mt][nt] = __builtin_amdgcn_mfma_f32_16x16x32_bf16(
                    af[mt], bfr[nt], acc[mt][nt], 0, 0, 0);
    }

    float bn[4];
#pragma unroll
    for (int nt = 0; nt < 4; nt++) bn[nt] = bias[n0 + wn * 64 + nt * 16 + l15];

    if (MODE == 0) {
        float* C = (float*)Cout;
#pragma unroll
        for (int mt = 0; mt < 4; mt++) {
            int m = m0 + wm * 64 + mt * 16 + quad * 4;
#pragma unroll
            for (int nt = 0; nt < 4; nt++) {
                int n = n0 + wn * 64 + nt * 16 + l15;
#pragma unroll
                for (int r = 0; r < 4; r++)
                    C[(size_t)(m + r) * 2048 + n] = acc[mt][nt][r] + bn[nt];
            }
        }
    } else if (MODE == 1) {
        u16* C = (u16*)Cout;
        const int h = n0 >> 7;
#pragma unroll
        for (int mt = 0; mt < 4; mt++) {
            int m = m0 + wm * 64 + mt * 16 + quad * 4;
            int b = m >> 11, t = m & 2047;
            size_t base = ((size_t)(b * Hh + h) * Tt + t) * Dd;
#pragma unroll
            for (int nt = 0; nt < 4; nt++) {
                int d = wn * 64 + nt * 16 + l15;
#pragma unroll
                for (int r = 0; r < 4; r++)
                    C[base + (size_t)r * Dd + d] = f2bf(acc[mt][nt][r] + bn[nt]);
            }
        }
    } else {  // MODE 2: V transposed (B,H,D,T), pack 4 consecutive t per lane
        u16* C = (u16*)Cout;
        const int h = n0 >> 7;
        const int b = m0 >> 11;
        const int tb = (m0 & 2047) + wm * 64;
#pragma unroll
        for (int mt = 0; mt < 4; mt++) {
            int t4 = tb + mt * 16 + quad * 4;
#pragma unroll
            for (int nt = 0; nt < 4; nt++) {
                int d = wn * 64 + nt * 16 + l15;
                union { ushort4 u; u16 s[4]; } pk;
#pragma unroll
                for (int r = 0; r < 4; r++) pk.s[r] = f2bf(acc[mt][nt][r] + bn[nt]);
                *(ushort4*)&C[((size_t)(b * Hh + h) * Dd + d) * Tt + t4] = pk.u;
            }
        }
    }
}

// ---- RoPE in-place on q,k bf16 (B,H,T,D)
__global__ __launch_bounds__(256) void rope_kernel(u16* __restrict__ q,
                                                   u16* __restrict__ k,
                                                   const float* __restrict__ cost,
                                                   const float* __restrict__ sint) {
    int p = blockIdx.x * 256 + threadIdx.x;    // B*H*T*64 pairs
    int i = p & 63;
    int t = (p >> 6) & 2047;
    float c = cost[t * 64 + i], s = sint[t * 64 + i];
    size_t off = (size_t)p * 2;
    ushort2 qv = *(ushort2*)(q + off);
    float q0 = bf2f(qv.x), q1 = bf2f(qv.y);
    qv.x = f2bf(q0 * c - q1 * s);
    qv.y = f2bf(q0 * s + q1 * c);
    *(ushort2*)(q + off) = qv;
    ushort2 kv = *(ushort2*)(k + off);
    float k0 = bf2f(kv.x), k1 = bf2f(kv.y);
    kv.x = f2bf(k0 * c - k1 * s);
    kv.y = f2bf(k0 * s + k1 * c);
    *(ushort2*)(k + off) = kv;
}

// ---- MFMA flash attention (causal). Q-tile 128 rows/block, K-tile 64.
// Per wave: 32 q rows. S^T = K*Q^T (D-frags: col=q=lane&15, row=kp=quad*4+r),
// P via LDS round-trip, O = P*V in C-layout (rows=q, cols=d).
// Q: (B,H,T,D) bf16, K: (B,H,T,D) bf16 (roped), Vt: (B,H,D,T) bf16.
// O out: (B,T,ATTN) bf16.
__global__ __launch_bounds__(256) void flash_mfma(const u16* __restrict__ Q,
                                                  const u16* __restrict__ K,
                                                  const u16* __restrict__ Vt,
                                                  u16* __restrict__ O) {
    __shared__ u16 Ks[64 * 128];      // [kp][d], granule-XOR-swizzled by kp&15
    __shared__ u16 Vs[128 * 64];      // [d][kp], granule-XOR-swizzled by d&7
    __shared__ u16 Ps[4][32 * 72];    // per-wave P [q][kp], stride 72
    __shared__ float als[4][32];
    __shared__ float lls[4][32];
    const int tid  = threadIdx.x;
    const int lane = tid & 63, w = tid >> 6;
    const int l15  = lane & 15, quad = lane >> 4;
    const int qt = blockIdx.x, bh = blockIdx.y;
    const int q0 = qt * 128;

    // Q fragments register-resident (B-operand of S^T): q=nt*16+l15, d=ks*32+quad*8
    short8 qf[2][4];
    const u16* Qb = Q + ((size_t)bh * Tt + q0 + w * 32 + l15) * Dd + quad * 8;
#pragma unroll
    for (int nt = 0; nt < 2; nt++)
#pragma unroll
        for (int ks = 0; ks < 4; ks++)
            qf[nt][ks] = *(const short8*)(Qb + nt * 16 * Dd + ks * 32);

    const f32x4 zero4 = {0.f, 0.f, 0.f, 0.f};
    f32x4 Oa[2][8];
#pragma unroll
    for (int mo = 0; mo < 2; mo++)
#pragma unroll
        for (int nt2 = 0; nt2 < 8; nt2++) Oa[mo][nt2] = zero4;
    float mrow[2] = {-INFINITY, -INFINITY};
    float lrow[2] = {0.f, 0.f};

    // staging pointers (wave w owns chunks 4w..4w+3 of each buffer)
    const u16* Kg[4]; const u16* Vg[4];
    u16* KsD[4]; u16* VsD[4];
#pragma unroll
    for (int cc = 0; cc < 4; cc++) {
        int kp = w * 16 + cc * 4 + quad;
        int gs = l15 ^ (cc * 4 + quad);          // kp & 15 == cc*4+quad (mod16)
        Kg[cc]  = K + ((size_t)bh * Tt + kp) * Dd + gs * 8;
        KsD[cc] = Ks + (w * 4 + cc) * 512;
        int d  = w * 32 + cc * 8 + (lane >> 3);
        int gv = (lane & 7) ^ (lane >> 3);       // d & 7 == lane>>3
        Vg[cc]  = Vt + ((size_t)bh * Dd + d) * Tt + gv * 8;
        VsD[cc] = Vs + (w * 4 + cc) * 512;
    }

    const float scale = 0.08838834764831843f;    // 1/sqrt(128)
    const int nkt = 2 * qt + 2;
    for (int kt = 0; kt < nkt; kt++) {
        __syncthreads();
#pragma unroll
        for (int cc = 0; cc < 4; cc++) gl_lds16(Kg[cc] + (size_t)kt * 64 * Dd, KsD[cc]);
#pragma unroll
        for (int cc = 0; cc < 4; cc++) gl_lds16(Vg[cc] + kt * 64, VsD[cc]);
        __syncthreads();

        // S^T = K * Q^T : sc[mt][nt], rows kp = mt*16+quad*4+r, cols q = nt*16+l15
        f32x4 sc[4][2];
#pragma unroll
        for (int mt = 0; mt < 4; mt++) { sc[mt][0] = zero4; sc[mt][1] = zero4; }
#pragma unroll
        for (int ks = 0; ks < 4; ks++) {
            short8 kf[4];
#pragma unroll
            for (int mt = 0; mt < 4; mt++)
                kf[mt] = *(const short8*)(Ks + (mt * 16 + l15) * 128 +
                                          (((ks * 4 + quad) ^ l15) * 8));
#pragma unroll
            for (int mt = 0; mt < 4; mt++) {
                sc[mt][0] = __builtin_amdgcn_mfma_f32_16x16x32_bf16(kf[mt], qf[0][ks], sc[mt][0], 0, 0, 0);
                sc[mt][1] = __builtin_amdgcn_mfma_f32_16x16x32_bf16(kf[mt], qf[1][ks], sc[mt][1], 0, 0, 0);
            }
        }

        // online softmax per q-column (row state replicated over the 4 quads)
#pragma unroll
        for (int nt = 0; nt < 2; nt++) {
            const int q_g = q0 + w * 32 + nt * 16 + l15;
            float sv[16];
#pragma unroll
            for (int mt = 0; mt < 4; mt++)
#pragma unroll
                for (int r = 0; r < 4; r++) {
                    int kp_g = kt * 64 + mt * 16 + quad * 4 + r;
                    float s = sc[mt][nt][r] * scale;
                    sv[mt * 4 + r] = (kp_g > q_g) ? -INFINITY : s;
                }
            float mx = sv[0];
#pragma unroll
            for (int e = 1; e < 16; e++) mx = fmaxf(mx, sv[e]);
            mx = fmaxf(mx, __shfl_xor(mx, 16, 64));
            mx = fmaxf(mx, __shfl_xor(mx, 32, 64));
            float mnew = fmaxf(mrow[nt], mx);
            float alpha = __expf(mrow[nt] - mnew);
            float pv[16], rs = 0.f;
#pragma unroll
            for (int e = 0; e < 16; e++) { pv[e] = __expf(sv[e] - mnew); rs += pv[e]; }
            rs += __shfl_xor(rs, 16, 64);
            rs += __shfl_xor(rs, 32, 64);
            lrow[nt] = lrow[nt] * alpha + rs;
            mrow[nt] = mnew;
            if (quad == 0) als[w][nt * 16 + l15] = alpha;
#pragma unroll
            for (int mt = 0; mt < 4; mt++) {
                union { ushort4 u; u16 s[4]; } pk;
#pragma unroll
                for (int r = 0; r < 4; r++) pk.s[r] = f2bf(pv[mt * 4 + r]);
                *(ushort4*)&Ps[w][(nt * 16 + l15) * 72 + mt * 16 + quad * 4] = pk.u;
            }
        }

        // rescale O by alpha (per O-row q = mo*16+quad*4+r)
        float ao[2][4];
#pragma unroll
        for (int mo = 0; mo < 2; mo++)
#pragma unroll
            for (int r = 0; r < 4; r++) ao[mo][r] = als[w][mo * 16 + quad * 4 + r];
#pragma unroll
        for (int mo = 0; mo < 2; mo++)
#pragma unroll
            for (int nt2 = 0; nt2 < 8; nt2++)
#pragma unroll
                for (int r = 0; r < 4; r++) Oa[mo][nt2][r] *= ao[mo][r];

        // O += P * V
#pragma unroll
        for (int ks2 = 0; ks2 < 2; ks2++) {
            short8 pf[2];
#pragma unroll
            for (int mo = 0; mo < 2; mo++)
                pf[mo] = *(const short8*)&Ps[w][(mo * 16 + l15) * 72 + ks2 * 32 + quad * 8];
#pragma unroll
            for (int nt2 = 0; nt2 < 8; nt2++) {
                short8 vf = *(const short8*)(Vs + (nt2 * 16 + l15) * 64 +
                                             (((ks2 * 4 + quad) ^ (l15 & 7)) * 8));
                Oa[0][nt2] = __builtin_amdgcn_mfma_f32_16x16x32_bf16(pf[0], vf, Oa[0][nt2], 0, 0, 0);
                Oa[1][nt2] = __builtin_amdgcn_mfma_f32_16x16x32_bf16(pf[1], vf, Oa[1][nt2], 0, 0, 0);
            }
        }
    }

    // epilogue: normalize by l, store bf16 (B,T,ATTN)
    if (quad == 0) { lls[w][l15] = lrow[0]; lls[w][16 + l15] = lrow[1]; }
    float li[2][4];
#pragma unroll
    for (int mo = 0; mo < 2; mo++)
#pragma unroll
        for (int r = 0; r < 4; r++) li[mo][r] = 1.f / lls[w][mo * 16 + quad * 4 + r];
    const int b = bh >> 4, h = bh & 15;
#pragma unroll
    for (int mo = 0; mo < 2; mo++)
#pragma unroll
        for (int r = 0; r < 4; r++) {
            size_t ro = ((size_t)b * Tt + q0 + w * 32 + mo * 16 + quad * 4 + r) * ATTN
                        + h * Dd;
#pragma unroll
            for (int nt2 = 0; nt2 < 8; nt2++)
                O[ro + nt2 * 16 + l15] = f2bf(Oa[mo][nt2][r] * li[mo][r]);
        }
}

extern "C" void kernel_launch(void* const* d_in, const int* in_sizes, int n_in,
                              void* d_out, int out_size, void* d_ws, size_t ws_size,
                              hipStream_t stream) {
    const float* x    = (const float*)d_in[0];
    const float* wq_w = (const float*)d_in[3];
    const float* wq_b = (const float*)d_in[4];
    const float* wk_w = (const float*)d_in[5];
    const float* wk_b = (const float*)d_in[6];
    const float* wv_w = (const float*)d_in[7];
    const float* wv_b = (const float*)d_in[8];
    const float* wo_w = (const float*)d_in[9];
    const float* wo_b = (const float*)d_in[10];

    char* ws = (char*)d_ws;
    u16*   qb  = (u16*)(ws);                    // 32 MiB bf16 (B,H,T,D)
    u16*   kb  = (u16*)(ws + 33554432);         // 32 MiB bf16 (B,H,T,D)
    u16*   vtb = (u16*)(ws + 67108864);         // 32 MiB bf16 (B,H,D,T)
    u16*   xb  = (u16*)(ws + 100663296);        // 32 MiB bf16 x (8192x2048)
    u16*   obb = xb;                            // flash out aliases xb (x dead)
    u16*   wqb = (u16*)(ws + 134217728);        // 8 MiB each
    u16*   wkb = (u16*)(ws + 142606336);
    u16*   wvb = (u16*)(ws + 150994944);
    u16*   wob = (u16*)(ws + 159383552);
    float* ct  = (float*)(ws + 167772160);      // 512 KiB
    float* st  = (float*)(ws + 168296448);      // 512 KiB

    freq_kernel<<<512, 256, 0, stream>>>(ct, st);
    cvt_kernel<<<16384, 256, 0, stream>>>(x, xb, 4194304);
    cvt_kernel<<<4096, 256, 0, stream>>>(wq_w, wqb, 1048576);
    cvt_kernel<<<4096, 256, 0, stream>>>(wk_w, wkb, 1048576);
    cvt_kernel<<<4096, 256, 0, stream>>>(wv_w, wvb, 1048576);
    cvt_kernel<<<4096, 256, 0, stream>>>(wo_w, wob, 1048576);

    dim3 gg(16, 64);
    gemm_mfma<1><<<gg, 256, 0, stream>>>(xb, wqb, wq_b, qb);
    gemm_mfma<1><<<gg, 256, 0, stream>>>(xb, wkb, wk_b, kb);
    gemm_mfma<2><<<gg, 256, 0, stream>>>(xb, wvb, wv_b, vtb);
    rope_kernel<<<32768, 256, 0, stream>>>(qb, kb, ct, st);
    flash_mfma<<<dim3(16, 64), 256, 0, stream>>>(qb, kb, vtb, obb);
    gemm_mfma<0><<<gg, 256, 0, stream>>>(obb, wob, wo_b, (float*)d_out);
}

// Round 3
// 793.490 us; speedup vs baseline: 8.1835x; 1.1690x over previous
//
#include <hip/hip_runtime.h>
#include <math.h>

#define Tt 2048
#define Hh 16
#define Dd 128
#define ATTN 2048

typedef unsigned short u16;
typedef __attribute__((ext_vector_type(8))) short short8;
typedef __attribute__((ext_vector_type(4))) float f32x4;

__device__ __forceinline__ float bf2f(u16 h) {
    union { unsigned int u; float f; } x;
    x.u = ((unsigned int)h) << 16;
    return x.f;
}
__device__ __forceinline__ u16 f2bf(float f) {
    union { float f; unsigned int u; } x;
    x.f = f;
    unsigned int r = x.u + 0x7fffu + ((x.u >> 16) & 1u);  // RNE
    return (u16)(r >> 16);
}
// async global->LDS, 16B per lane; lptr is wave-uniform base, HW adds lane*16.
__device__ __forceinline__ void gl_lds16(const void* g, void* l) {
    __builtin_amdgcn_global_load_lds(
        (const __attribute__((address_space(1))) unsigned int*)g,
        (__attribute__((address_space(3))) unsigned int*)l, 16, 0, 0);
}

// ---- RoPE cos/sin table (reference ignores freqs_cos/sin inputs; recompute).
__global__ __launch_bounds__(256) void freq_kernel(float* __restrict__ cost,
                                                   float* __restrict__ sint) {
    int idx = blockIdx.x * 256 + threadIdx.x;   // Tt*64
    if (idx >= Tt * 64) return;
    int t = idx >> 6, i = idx & 63;
    double inv = exp(-((double)(2 * i) / 128.0) * log(10000.0));
    double ang = (double)t * inv;
    cost[idx] = (float)cos(ang);
    sint[idx] = (float)sin(ang);
}

// ---- fp32 -> bf16 bulk convert (vectorized), n4 = elems/4
__global__ __launch_bounds__(256) void cvt_kernel(const float* __restrict__ in,
                                                  u16* __restrict__ out, int n4) {
    int i = blockIdx.x * 256 + threadIdx.x;
    if (i >= n4) return;
    float4 v = *(const float4*)(in + (size_t)i * 4);
    union { ushort4 u; u16 s[4]; } pk;
    pk.s[0] = f2bf(v.x); pk.s[1] = f2bf(v.y);
    pk.s[2] = f2bf(v.z); pk.s[3] = f2bf(v.w);
    *(ushort4*)(out + (size_t)i * 4) = pk.u;
}

// ---- bf16 MFMA GEMM: C[m,n] = sum_k A[m,k]*W[n,k] + bias[n]
// A: M x 2048 bf16 row-major, W: 2048 x 2048 bf16 row-major (B^T form).
// 128x128 tile, BK=32, 256 thr (4 waves, 2x2 wave grid, 64x64 each).
// MODE 0: fp32 (M,2048). MODE 1: bf16 (B,H,T,D). MODE 2: bf16 (B,H,D,T).
template<int MODE>
__global__ __launch_bounds__(256) void gemm_mfma(const u16* __restrict__ A,
                                                 const u16* __restrict__ W,
                                                 const float* __restrict__ bias,
                                                 void* __restrict__ Cout) {
    __shared__ u16 As[128 * 32];
    __shared__ u16 Ws[128 * 32];
    const int tid  = threadIdx.x;
    const int lane = tid & 63, w = tid >> 6;
    const int l15  = lane & 15, quad = lane >> 4;
    const int wm = w & 1, wn = w >> 1;
    const int m0 = blockIdx.y * 128, n0 = blockIdx.x * 128;

    const f32x4 zero4 = {0.f, 0.f, 0.f, 0.f};
    f32x4 acc[4][4];
#pragma unroll
    for (int mt = 0; mt < 4; mt++)
#pragma unroll
        for (int nt = 0; nt < 4; nt++) acc[mt][nt] = zero4;

    const int srow = w * 32 + (lane >> 2);
    const int scol = (lane & 3) * 8;
    const u16* Ag = A + (size_t)(m0 + srow) * 2048 + scol;
    const u16* Wg = W + (size_t)(n0 + srow) * 2048 + scol;
    u16* AsW = As + w * 1024;
    u16* WsW = Ws + w * 1024;

    for (int k0 = 0; k0 < 2048; k0 += 32) {
        __syncthreads();
        gl_lds16(Ag, AsW);
        gl_lds16(Ag + (size_t)16 * 2048, AsW + 512);
        gl_lds16(Wg, WsW);
        gl_lds16(Wg + (size_t)16 * 2048, WsW + 512);
        Ag += 32; Wg += 32;
        __syncthreads();
        const u16* ar = As + (wm * 64 + l15) * 32 + quad * 8;
        const u16* br = Ws + (wn * 64 + l15) * 32 + quad * 8;
        short8 af[4], bfr[4];
#pragma unroll
        for (int mt = 0; mt < 4; mt++) af[mt] = *(const short8*)(ar + mt * 512);
#pragma unroll
        for (int nt = 0; nt < 4; nt++) bfr[nt] = *(const short8*)(br + nt * 512);
#pragma unroll
        for (int mt = 0; mt < 4; mt++)
#pragma unroll
            for (int nt = 0; nt < 4; nt++)
                acc[mt][nt] = __builtin_amdgcn_mfma_f32_16x16x32_bf16(
                    af[mt], bfr[nt], acc[mt][nt], 0, 0, 0);
    }

    float bn[4];
#pragma unroll
    for (int nt = 0; nt < 4; nt++) bn[nt] = bias[n0 + wn * 64 + nt * 16 + l15];

    if (MODE == 0) {
        float* C = (float*)Cout;
#pragma unroll
        for (int mt = 0; mt < 4; mt++) {
            int m = m0 + wm * 64 + mt * 16 + quad * 4;
#pragma unroll
            for (int nt = 0; nt < 4; nt++) {
                int n = n0 + wn * 64 + nt * 16 + l15;
#pragma unroll
                for (int r = 0; r < 4; r++)
                    C[(size_t)(m + r) * 2048 + n] = acc[mt][nt][r] + bn[nt];
            }
        }
    } else if (MODE == 1) {
        u16* C = (u16*)Cout;
        const int h = n0 >> 7;
#pragma unroll
        for (int mt = 0; mt < 4; mt++) {
            int m = m0 + wm * 64 + mt * 16 + quad * 4;
            int b = m >> 11, t = m & 2047;
            size_t base = ((size_t)(b * Hh + h) * Tt + t) * Dd;
#pragma unroll
            for (int nt = 0; nt < 4; nt++) {
                int d = wn * 64 + nt * 16 + l15;
#pragma unroll
                for (int r = 0; r < 4; r++)
                    C[base + (size_t)r * Dd + d] = f2bf(acc[mt][nt][r] + bn[nt]);
            }
        }
    } else {  // MODE 2: V transposed (B,H,D,T), pack 4 consecutive t per lane
        u16* C = (u16*)Cout;
        const int h = n0 >> 7;
        const int b = m0 >> 11;
        const int tb = (m0 & 2047) + wm * 64;
#pragma unroll
        for (int mt = 0; mt < 4; mt++) {
            int t4 = tb + mt * 16 + quad * 4;
#pragma unroll
            for (int nt = 0; nt < 4; nt++) {
                int d = wn * 64 + nt * 16 + l15;
                union { ushort4 u; u16 s[4]; } pk;
#pragma unroll
                for (int r = 0; r < 4; r++) pk.s[r] = f2bf(acc[mt][nt][r] + bn[nt]);
                *(ushort4*)&C[((size_t)(b * Hh + h) * Dd + d) * Tt + t4] = pk.u;
            }
        }
    }
}

// ---- RoPE in-place on q,k bf16 (B,H,T,D).
// Q additionally pre-scaled by 1/sqrt(D) * log2(e): flash softmax runs in the
// exp2 domain with no per-element scale mul (rotation is linear -> legal fold).
#define QSCALE 0.12751743f
__global__ __launch_bounds__(256) void rope_kernel(u16* __restrict__ q,
                                                   u16* __restrict__ k,
                                                   const float* __restrict__ cost,
                                                   const float* __restrict__ sint) {
    int p = blockIdx.x * 256 + threadIdx.x;    // B*H*T*64 pairs
    int i = p & 63;
    int t = (p >> 6) & 2047;
    float c = cost[t * 64 + i], s = sint[t * 64 + i];
    size_t off = (size_t)p * 2;
    ushort2 qv = *(ushort2*)(q + off);
    float q0 = bf2f(qv.x), q1 = bf2f(qv.y);
    qv.x = f2bf((q0 * c - q1 * s) * QSCALE);
    qv.y = f2bf((q0 * s + q1 * c) * QSCALE);
    *(ushort2*)(q + off) = qv;
    ushort2 kv = *(ushort2*)(k + off);
    float k0 = bf2f(kv.x), k1 = bf2f(kv.y);
    kv.x = f2bf(k0 * c - k1 * s);
    kv.y = f2bf(k0 * s + k1 * c);
    *(ushort2*)(k + off) = kv;
}

// ---- MFMA flash attention (causal), load-balanced pairing:
// block bx handles q-tiles (15-bx) then (bx) -> exactly 34 K-iters per block.
// Grid 8x64 = 512 uniform blocks = 2 blocks/CU, fully co-resident.
__global__ __launch_bounds__(256) void flash_mfma(const u16* __restrict__ Q,
                                                  const u16* __restrict__ K,
                                                  const u16* __restrict__ Vt,
                                                  u16* __restrict__ O) {
    __shared__ u16 Ks[64 * 128];      // [kp][d], granule-XOR-swizzled by kp&15
    __shared__ u16 Vs[128 * 64];      // [d][kp], granule-XOR-swizzled by d&7
    __shared__ u16 Ps[4][32 * 72];    // per-wave P [q][kp], stride 72
    __shared__ float als[4][32];
    __shared__ float lls[4][32];
    const int tid  = threadIdx.x;
    const int lane = tid & 63, w = tid >> 6;
    const int l15  = lane & 15, quad = lane >> 4;
    const int bx = blockIdx.x, bh = blockIdx.y;

    // staging pointers (wave w owns chunks 4w..4w+3 of each buffer); bh-only
    const u16* Kg[4]; const u16* Vg[4];
    u16* KsD[4]; u16* VsD[4];
#pragma unroll
    for (int cc = 0; cc < 4; cc++) {
        int kp = w * 16 + cc * 4 + quad;
        int gs = l15 ^ (cc * 4 + quad);
        Kg[cc]  = K + ((size_t)bh * Tt + kp) * Dd + gs * 8;
        KsD[cc] = Ks + (w * 4 + cc) * 512;
        int d  = w * 32 + cc * 8 + (lane >> 3);
        int gv = (lane & 7) ^ (lane >> 3);
        Vg[cc]  = Vt + ((size_t)bh * Dd + d) * Tt + gv * 8;
        VsD[cc] = Vs + (w * 4 + cc) * 512;
    }

    const f32x4 zero4 = {0.f, 0.f, 0.f, 0.f};

    for (int ph = 0; ph < 2; ph++) {
        const int qt = ph ? bx : 15 - bx;
        const int q0 = qt * 128;

        // Q fragments (B-operand of S^T): q=nt*16+l15, d=ks*32+quad*8
        short8 qf[2][4];
        const u16* Qb = Q + ((size_t)bh * Tt + q0 + w * 32 + l15) * Dd + quad * 8;
#pragma unroll
        for (int nt = 0; nt < 2; nt++)
#pragma unroll
            for (int ks = 0; ks < 4; ks++)
                qf[nt][ks] = *(const short8*)(Qb + nt * 16 * Dd + ks * 32);

        f32x4 Oa[2][8];
#pragma unroll
        for (int mo = 0; mo < 2; mo++)
#pragma unroll
            for (int nt2 = 0; nt2 < 8; nt2++) Oa[mo][nt2] = zero4;
        float mrow[2] = {-INFINITY, -INFINITY};
        float lrow[2] = {0.f, 0.f};

        const int nkt = 2 * qt + 2;
        for (int kt = 0; kt < nkt; kt++) {
            __syncthreads();
#pragma unroll
            for (int cc = 0; cc < 4; cc++) gl_lds16(Kg[cc] + (size_t)kt * 64 * Dd, KsD[cc]);
#pragma unroll
            for (int cc = 0; cc < 4; cc++) gl_lds16(Vg[cc] + kt * 64, VsD[cc]);
            __syncthreads();

            // wave-level skip: tile fully masked for this wave's 32 q-rows
            if (kt * 64 > q0 + w * 32 + 31) continue;  // barriers already done

            // S^T = K * Q^T : rows kp = mt*16+quad*4+r, cols q = nt*16+l15
            f32x4 sc[4][2];
#pragma unroll
            for (int mt = 0; mt < 4; mt++) { sc[mt][0] = zero4; sc[mt][1] = zero4; }
#pragma unroll
            for (int ks = 0; ks < 4; ks++) {
                short8 kf[4];
#pragma unroll
                for (int mt = 0; mt < 4; mt++)
                    kf[mt] = *(const short8*)(Ks + (mt * 16 + l15) * 128 +
                                              (((ks * 4 + quad) ^ l15) * 8));
#pragma unroll
                for (int mt = 0; mt < 4; mt++) {
                    sc[mt][0] = __builtin_amdgcn_mfma_f32_16x16x32_bf16(kf[mt], qf[0][ks], sc[mt][0], 0, 0, 0);
                    sc[mt][1] = __builtin_amdgcn_mfma_f32_16x16x32_bf16(kf[mt], qf[1][ks], sc[mt][1], 0, 0, 0);
                }
            }

            const bool diag = (kt >= 2 * qt);   // only diagonal tiles need mask
            // online softmax in exp2 domain (scale*log2e pre-folded into Q)
#pragma unroll
            for (int nt = 0; nt < 2; nt++) {
                const int q_g = q0 + w * 32 + nt * 16 + l15;
                float sv[16];
#pragma unroll
                for (int mt = 0; mt < 4; mt++)
#pragma unroll
                    for (int r = 0; r < 4; r++)
                        sv[mt * 4 + r] = sc[mt][nt][r];
                if (diag) {
#pragma unroll
                    for (int mt = 0; mt < 4; mt++)
#pragma unroll
                        for (int r = 0; r < 4; r++) {
                            int kp_g = kt * 64 + mt * 16 + quad * 4 + r;
                            if (kp_g > q_g) sv[mt * 4 + r] = -INFINITY;
                        }
                }
                float mx = sv[0];
#pragma unroll
                for (int e = 1; e < 16; e++) mx = fmaxf(mx, sv[e]);
                mx = fmaxf(mx, __shfl_xor(mx, 16, 64));
                mx = fmaxf(mx, __shfl_xor(mx, 32, 64));
                float mnew = fmaxf(mrow[nt], mx);
                float alpha = exp2f(mrow[nt] - mnew);
                float pv[16], rs = 0.f;
#pragma unroll
                for (int e = 0; e < 16; e++) { pv[e] = exp2f(sv[e] - mnew); rs += pv[e]; }
                rs += __shfl_xor(rs, 16, 64);
                rs += __shfl_xor(rs, 32, 64);
                lrow[nt] = lrow[nt] * alpha + rs;
                mrow[nt] = mnew;
                if (quad == 0) als[w][nt * 16 + l15] = alpha;
#pragma unroll
                for (int mt = 0; mt < 4; mt++) {
                    union { ushort4 u; u16 s[4]; } pk;
#pragma unroll
                    for (int r = 0; r < 4; r++) pk.s[r] = f2bf(pv[mt * 4 + r]);
                    *(ushort4*)&Ps[w][(nt * 16 + l15) * 72 + mt * 16 + quad * 4] = pk.u;
                }
            }

            // rescale O by alpha (per O-row q = mo*16+quad*4+r)
            float ao[2][4];
#pragma unroll
            for (int mo = 0; mo < 2; mo++)
#pragma unroll
                for (int r = 0; r < 4; r++) ao[mo][r] = als[w][mo * 16 + quad * 4 + r];
#pragma unroll
            for (int mo = 0; mo < 2; mo++)
#pragma unroll
                for (int nt2 = 0; nt2 < 8; nt2++)
#pragma unroll
                    for (int r = 0; r < 4; r++) Oa[mo][nt2][r] *= ao[mo][r];

            // O += P * V
#pragma unroll
            for (int ks2 = 0; ks2 < 2; ks2++) {
                short8 pf[2];
#pragma unroll
                for (int mo = 0; mo < 2; mo++)
                    pf[mo] = *(const short8*)&Ps[w][(mo * 16 + l15) * 72 + ks2 * 32 + quad * 8];
#pragma unroll
                for (int nt2 = 0; nt2 < 8; nt2++) {
                    short8 vf = *(const short8*)(Vs + (nt2 * 16 + l15) * 64 +
                                                 (((ks2 * 4 + quad) ^ (l15 & 7)) * 8));
                    Oa[0][nt2] = __builtin_amdgcn_mfma_f32_16x16x32_bf16(pf[0], vf, Oa[0][nt2], 0, 0, 0);
                    Oa[1][nt2] = __builtin_amdgcn_mfma_f32_16x16x32_bf16(pf[1], vf, Oa[1][nt2], 0, 0, 0);
                }
            }
        }

        // epilogue: normalize by l, store bf16 (B,T,ATTN)
        if (quad == 0) { lls[w][l15] = lrow[0]; lls[w][16 + l15] = lrow[1]; }
        float li[2][4];
#pragma unroll
        for (int mo = 0; mo < 2; mo++)
#pragma unroll
            for (int r = 0; r < 4; r++) li[mo][r] = 1.f / lls[w][mo * 16 + quad * 4 + r];
        const int b = bh >> 4, h = bh & 15;
#pragma unroll
        for (int mo = 0; mo < 2; mo++)
#pragma unroll
            for (int r = 0; r < 4; r++) {
                size_t ro = ((size_t)b * Tt + q0 + w * 32 + mo * 16 + quad * 4 + r) * ATTN
                            + h * Dd;
#pragma unroll
                for (int nt2 = 0; nt2 < 8; nt2++)
                    O[ro + nt2 * 16 + l15] = f2bf(Oa[mo][nt2][r] * li[mo][r]);
            }
    }
}

extern "C" void kernel_launch(void* const* d_in, const int* in_sizes, int n_in,
                              void* d_out, int out_size, void* d_ws, size_t ws_size,
                              hipStream_t stream) {
    const float* x    = (const float*)d_in[0];
    const float* wq_w = (const float*)d_in[3];
    const float* wq_b = (const float*)d_in[4];
    const float* wk_w = (const float*)d_in[5];
    const float* wk_b = (const float*)d_in[6];
    const float* wv_w = (const float*)d_in[7];
    const float* wv_b = (const float*)d_in[8];
    const float* wo_w = (const float*)d_in[9];
    const float* wo_b = (const float*)d_in[10];

    char* ws = (char*)d_ws;
    u16*   qb  = (u16*)(ws);                    // 32 MiB bf16 (B,H,T,D)
    u16*   kb  = (u16*)(ws + 33554432);         // 32 MiB bf16 (B,H,T,D)
    u16*   vtb = (u16*)(ws + 67108864);         // 32 MiB bf16 (B,H,D,T)
    u16*   xb  = (u16*)(ws + 100663296);        // 32 MiB bf16 x (8192x2048)
    u16*   obb = xb;                            // flash out aliases xb (x dead)
    u16*   wqb = (u16*)(ws + 134217728);        // 8 MiB each
    u16*   wkb = (u16*)(ws + 142606336);
    u16*   wvb = (u16*)(ws + 150994944);
    u16*   wob = (u16*)(ws + 159383552);
    float* ct  = (float*)(ws + 167772160);      // 512 KiB
    float* st  = (float*)(ws + 168296448);      // 512 KiB

    freq_kernel<<<512, 256, 0, stream>>>(ct, st);
    cvt_kernel<<<16384, 256, 0, stream>>>(x, xb, 4194304);
    cvt_kernel<<<4096, 256, 0, stream>>>(wq_w, wqb, 1048576);
    cvt_kernel<<<4096, 256, 0, stream>>>(wk_w, wkb, 1048576);
    cvt_kernel<<<4096, 256, 0, stream>>>(wv_w, wvb, 1048576);
    cvt_kernel<<<4096, 256, 0, stream>>>(wo_w, wob, 1048576);

    dim3 gg(16, 64);
    gemm_mfma<1><<<gg, 256, 0, stream>>>(xb, wqb, wq_b, qb);
    gemm_mfma<1><<<gg, 256, 0, stream>>>(xb, wkb, wk_b, kb);
    gemm_mfma<2><<<gg, 256, 0, stream>>>(xb, wvb, wv_b, vtb);
    rope_kernel<<<32768, 256, 0, stream>>>(qb, kb, ct, st);
    flash_mfma<<<dim3(8, 64), 256, 0, stream>>>(qb, kb, vtb, obb);
    gemm_mfma<0><<<gg, 256, 0, stream>>>(obb, wob, wo_b, (float*)d_out);
}